// Round 2
// baseline (692.288 us; speedup 1.0000x reference)
//
#include <hip/hip_runtime.h>
#include <math.h>

#define BATCH 16384
#define NCLS  8192
#define NTAIL 16
#define GRID  2048
#define RPB   (BATCH / GRID)   // 8 rows per block, strided by GRID

// ws layout: [0, BATCH*4)            p_true  (float[BATCH])
//            [BATCH*4, BATCH*4+64)   tail counts (int[NTAIL])

__global__ void init_kernel(float* __restrict__ out, int* __restrict__ counts) {
    int t = threadIdx.x;
    if (t < NTAIL) counts[t] = 0;
    if (t == 0)    out[0] = 0.0f;
}

// Barrier that does NOT drain vmcnt: LDS writes are ordered with lgkmcnt(0),
// but global loads issued for the NEXT row stay in flight across the barrier.
// (__syncthreads would emit s_waitcnt vmcnt(0) and kill the pipeline.)
__device__ __forceinline__ void sync_lds() {
    asm volatile("s_waitcnt lgkmcnt(0)" ::: "memory");
    __builtin_amdgcn_s_barrier();
}

// Issue-only: 8 float4 loads + label load. No use of the data here, so the
// compiler does not insert a vmcnt wait (nan-fix is deferred to compute).
__device__ __forceinline__ void load_row(const float* __restrict__ x,
                                         const int* __restrict__ labels,
                                         int row, int t,
                                         float4 v[8], int& lab) {
    const float4* rowp = (const float4*)(x + (size_t)row * NCLS);
    #pragma unroll
    for (int k = 0; k < 8; ++k) v[k] = rowp[t + k * 256];
    lab = labels[row];
}

__device__ __forceinline__ void compute_row(float4 v[8], int lab, int row, int t,
                                            float* __restrict__ p_true,
                                            int* __restrict__ counts,
                                            float* sm, int* si, float* ssum,
                                            float* sxt) {
    // nan_to_num (first use of v => compiler waits on this row's loads only;
    // the next row's loads, issued later, remain outstanding).
    #pragma unroll
    for (int k = 0; k < 8; ++k) {
        v[k].x = (v[k].x == v[k].x) ? v[k].x : 0.0f;
        v[k].y = (v[k].y == v[k].y) ? v[k].y : 0.0f;
        v[k].z = (v[k].z == v[k].z) ? v[k].z : 0.0f;
        v[k].w = (v[k].w == v[k].w) ? v[k].w : 0.0f;
    }

    // True-class logit is already in registers: exactly one thread owns
    // column lab (2048 float4 slots cover the row). Compile-time-indexed
    // selection; no global reload, no dependent-load tail.
    const int labq = lab >> 2, labc = lab & 3;
    float xt = 0.0f;
    bool  own = false;
    #pragma unroll
    for (int k = 0; k < 8; ++k) {
        if (labq == t + k * 256) {
            float e = (labc == 0) ? v[k].x
                    : (labc == 1) ? v[k].y
                    : (labc == 2) ? v[k].z : v[k].w;
            xt = e; own = true;
        }
    }

    // Per-thread max/argmax: 4 independent chains, strict '>' keeps first
    // occurrence within a chain; chains merged with min-index tie-break.
    float mc0 = -INFINITY, mc1 = -INFINITY, mc2 = -INFINITY, mc3 = -INFINITY;
    int   ic0 = 0, ic1 = 0, ic2 = 0, ic3 = 0;
    #pragma unroll
    for (int k = 0; k < 8; ++k) {
        const int c0 = (t + k * 256) * 4;
        if (v[k].x > mc0) { mc0 = v[k].x; ic0 = c0;     }
        if (v[k].y > mc1) { mc1 = v[k].y; ic1 = c0 + 1; }
        if (v[k].z > mc2) { mc2 = v[k].z; ic2 = c0 + 2; }
        if (v[k].w > mc3) { mc3 = v[k].w; ic3 = c0 + 3; }
    }
    float m = mc0; int idx = ic0;
    if (mc1 > m || (mc1 == m && ic1 < idx)) { m = mc1; idx = ic1; }
    if (mc2 > m || (mc2 == m && ic2 < idx)) { m = mc2; idx = ic2; }
    if (mc3 > m || (mc3 == m && ic3 < idx)) { m = mc3; idx = ic3; }

    #pragma unroll
    for (int off = 32; off; off >>= 1) {
        float m2 = __shfl_xor(m, off);
        int   i2 = __shfl_xor(idx, off);
        if (m2 > m || (m2 == m && i2 < idx)) { m = m2; idx = i2; }
    }

    const int wave = t >> 6;
    if ((t & 63) == 0) { sm[wave] = m; si[wave] = idx; }
    sync_lds();                                  // barrier #1 (no vmcnt drain)

    float M = sm[0]; int I = si[0];
    #pragma unroll
    for (int w = 1; w < 4; ++w) {
        if (sm[w] > M || (sm[w] == M && si[w] < I)) { M = sm[w]; I = si[w]; }
    }

    // Sum of exp(x - M): 4 independent accumulators, branch-free.
    float s0 = 0.0f, s1 = 0.0f, s2 = 0.0f, s3 = 0.0f;
    #pragma unroll
    for (int k = 0; k < 8; ++k) {
        s0 += __expf(v[k].x - M);
        s1 += __expf(v[k].y - M);
        s2 += __expf(v[k].z - M);
        s3 += __expf(v[k].w - M);
    }
    float s = (s0 + s1) + (s2 + s3);
    #pragma unroll
    for (int off = 32; off; off >>= 1) s += __shfl_xor(s, off);
    if ((t & 63) == 0) ssum[wave] = s;
    if (own) *sxt = xt;          // written between barrier #1 and barrier #2:
                                 // safely ordered vs t0's read of the previous row
    sync_lds();                                  // barrier #2 (no vmcnt drain)

    if (t == 0) {
        const float stot = ssum[0] + ssum[1] + ssum[2] + ssum[3];
        p_true[row] = __expf(*sxt - M) / stot;
        if (I >= NCLS - NTAIL) atomicAdd(&counts[I - (NCLS - NTAIL)], 1);
    }
}

// Persistent blocks: GRID blocks, each owns RPB=8 rows (stride GRID), with a
// ping-pong register double-buffer so the next row's loads are in flight
// while the current row's reduction runs. Barriers never drain vmcnt.
__global__ __launch_bounds__(256) void row_kernel(const float* __restrict__ x,
                                                  const int* __restrict__ labels,
                                                  float* __restrict__ p_true,
                                                  int* __restrict__ counts) {
    const int t = threadIdx.x;
    __shared__ float sm[4];
    __shared__ int   si[4];
    __shared__ float ssum[4];
    __shared__ float sxt;

    float4 A[8], B[8];
    int labA, labB;
    const int r0 = blockIdx.x;

    load_row(x, labels, r0, t, A, labA);
    #pragma unroll
    for (int j = 0; j < RPB; j += 2) {
        load_row(x, labels, r0 + (j + 1) * GRID, t, B, labB);
        compute_row(A, labA, r0 + j * GRID, t, p_true, counts, sm, si, ssum, &sxt);
        if (j + 2 < RPB) load_row(x, labels, r0 + (j + 2) * GRID, t, A, labA);
        compute_row(B, labB, r0 + (j + 1) * GRID, t, p_true, counts, sm, si, ssum, &sxt);
    }
}

__global__ __launch_bounds__(256) void penalty_kernel(const float* __restrict__ p_true,
                                                      const int* __restrict__ labels,
                                                      const int* __restrict__ prev_counts,
                                                      const int* __restrict__ counts,
                                                      float* __restrict__ out) {
    const int i = blockIdx.x * 256 + threadIdx.x;
    const float p = p_true[i];
    const int lab = labels[i];
    float w = 1.0f;
    if (lab >= NCLS - NTAIL) {
        const int prev = prev_counts[lab];
        const int curr = counts[lab - (NCLS - NTAIL)];
        w = (prev > 0 && curr < prev) ? 4.0f
          : (prev > 0 && curr > prev) ? 2.0f
          : 3.0f;
    }
    float pen = -logf(p + 1e-7f) * (1.0f - p) * w;

    #pragma unroll
    for (int off = 32; off; off >>= 1) pen += __shfl_down(pen, off);

    __shared__ float acc[4];
    if ((threadIdx.x & 63) == 0) acc[threadIdx.x >> 6] = pen;
    __syncthreads();
    if (threadIdx.x == 0) {
        const float bs = acc[0] + acc[1] + acc[2] + acc[3];
        atomicAdd(out, bs * (0.1f / (float)BATCH));
    }
}

extern "C" void kernel_launch(void* const* d_in, const int* in_sizes, int n_in,
                              void* d_out, int out_size, void* d_ws, size_t ws_size,
                              hipStream_t stream) {
    const float* x           = (const float*)d_in[0];
    const int*   labels      = (const int*)  d_in[1];
    const int*   prev_counts = (const int*)  d_in[2];
    // d_in[3] (tail_mask) is deterministic: class >= NCLS-NTAIL — recomputed inline.

    float* out    = (float*)d_out;
    float* p_true = (float*)d_ws;
    int*   counts = (int*)((char*)d_ws + BATCH * sizeof(float));

    init_kernel<<<1, 64, 0, stream>>>(out, counts);
    row_kernel<<<GRID, 256, 0, stream>>>(x, labels, p_true, counts);
    penalty_kernel<<<BATCH / 256, 256, 0, stream>>>(p_true, labels, prev_counts, counts, out);
}

// Round 3
// 680.522 us; speedup vs baseline: 1.0173x; 1.0173x over previous
//
#include <hip/hip_runtime.h>
#include <math.h>

#define BATCH 16384
#define NCLS  8192
#define NTAIL 16
#define NSEG  4                 // wave-owned segments per row
#define SEGLEN (NCLS / NSEG)    // 2048 elems = 512 float4 = 64 lanes x 8 float4

// ws layout:
//   [0, BATCH*4)                          p_true  float[BATCH]
//   [BATCH*4, BATCH*4+64)                 counts  int[NTAIL]
//   [OFF_PM, +BATCH*NSEG*4)               pm float[BATCH*NSEG]  (per-seg max,  float4/row)
//   [OFF_PS, +BATCH*NSEG*4)               ps float[BATCH*NSEG]  (per-seg expsum vs seg max)
//   [OFF_PI, +BATCH*NSEG*4)               pi int  [BATCH*NSEG]  (per-seg argmax)
#define OFF_PM (BATCH * 4 + 256)
#define OFF_PS (OFF_PM + BATCH * NSEG * 4)
#define OFF_PI (OFF_PS + BATCH * NSEG * 4)

__global__ void init_kernel(float* __restrict__ out, int* __restrict__ counts) {
    int t = threadIdx.x;
    if (t < NTAIL) counts[t] = 0;
    if (t == 0)    out[0] = 0.0f;
}

// Phase 1: pure streaming. Block b = row b; wave w = segment w. No LDS, no
// barriers, no per-row serial tail — structurally identical to the harness
// fill (which achieves 6.35 TB/s), except reads instead of writes.
__global__ __launch_bounds__(256) void partial_kernel(const float* __restrict__ x,
                                                      float* __restrict__ pm,
                                                      float* __restrict__ ps,
                                                      int* __restrict__ pi) {
    const int t    = threadIdx.x;
    const int seg  = t >> 6;          // wave index = segment
    const int lane = t & 63;
    const int row  = blockIdx.x;
    const float4* segp = (const float4*)(x + (size_t)row * NCLS + seg * SEGLEN);

    float4 v[8];
    #pragma unroll
    for (int k = 0; k < 8; ++k) v[k] = segp[lane + k * 64];

    #pragma unroll
    for (int k = 0; k < 8; ++k) {
        v[k].x = (v[k].x == v[k].x) ? v[k].x : 0.0f;
        v[k].y = (v[k].y == v[k].y) ? v[k].y : 0.0f;
        v[k].z = (v[k].z == v[k].z) ? v[k].z : 0.0f;
        v[k].w = (v[k].w == v[k].w) ? v[k].w : 0.0f;
    }

    // Per-lane max/argmax: 4 independent chains (strict '>' keeps first
    // occurrence within a chain), merged with min-index tie-break.
    float mc0 = -INFINITY, mc1 = -INFINITY, mc2 = -INFINITY, mc3 = -INFINITY;
    int   ic0 = 0, ic1 = 0, ic2 = 0, ic3 = 0;
    #pragma unroll
    for (int k = 0; k < 8; ++k) {
        const int c0 = seg * SEGLEN + (lane + k * 64) * 4;
        if (v[k].x > mc0) { mc0 = v[k].x; ic0 = c0;     }
        if (v[k].y > mc1) { mc1 = v[k].y; ic1 = c0 + 1; }
        if (v[k].z > mc2) { mc2 = v[k].z; ic2 = c0 + 2; }
        if (v[k].w > mc3) { mc3 = v[k].w; ic3 = c0 + 3; }
    }
    float m = mc0; int idx = ic0;
    if (mc1 > m || (mc1 == m && ic1 < idx)) { m = mc1; idx = ic1; }
    if (mc2 > m || (mc2 == m && ic2 < idx)) { m = mc2; idx = ic2; }
    if (mc3 > m || (mc3 == m && ic3 < idx)) { m = mc3; idx = ic3; }

    // Wave butterfly: all lanes converge to the segment (m, idx).
    #pragma unroll
    for (int off = 32; off; off >>= 1) {
        float m2 = __shfl_xor(m, off);
        int   i2 = __shfl_xor(idx, off);
        if (m2 > m || (m2 == m && i2 < idx)) { m = m2; idx = i2; }
    }

    // Segment exp-sum vs the (now wave-uniform) segment max. 4 independent
    // accumulators, branch-free, exps issue at throughput rate.
    float s0 = 0.0f, s1 = 0.0f, s2 = 0.0f, s3 = 0.0f;
    #pragma unroll
    for (int k = 0; k < 8; ++k) {
        s0 += __expf(v[k].x - m);
        s1 += __expf(v[k].y - m);
        s2 += __expf(v[k].z - m);
        s3 += __expf(v[k].w - m);
    }
    float s = (s0 + s1) + (s2 + s3);
    #pragma unroll
    for (int off = 32; off; off >>= 1) s += __shfl_xor(s, off);

    if (lane == 0) {
        const int p = row * NSEG + seg;
        pm[p] = m; ps[p] = s; pi[p] = idx;
    }
}

// Phase 2: one thread per row merges the 4 segment partials (log-sum-exp
// rescale), gathers the true-class logit, writes p_true, bumps tail counts.
__global__ __launch_bounds__(256) void combine_kernel(const float* __restrict__ x,
                                                      const int* __restrict__ labels,
                                                      const float* __restrict__ pm,
                                                      const float* __restrict__ ps,
                                                      const int* __restrict__ pi,
                                                      float* __restrict__ p_true,
                                                      int* __restrict__ counts) {
    const int r = blockIdx.x * 256 + threadIdx.x;
    const float4 m4 = *(const float4*)(pm + r * NSEG);
    const float4 s4 = *(const float4*)(ps + r * NSEG);
    const int4   i4 = *(const int4*)  (pi + r * NSEG);
    const int lab = labels[r];

    // Segments are index-ordered, so strict '>' keeps the lowest index on ties.
    float M = m4.x; int I = i4.x;
    if (m4.y > M) { M = m4.y; I = i4.y; }
    if (m4.z > M) { M = m4.z; I = i4.z; }
    if (m4.w > M) { M = m4.w; I = i4.w; }

    const float S = s4.x * __expf(m4.x - M) + s4.y * __expf(m4.y - M)
                  + s4.z * __expf(m4.z - M) + s4.w * __expf(m4.w - M);

    float xt = x[(size_t)r * NCLS + lab];
    xt = (xt == xt) ? xt : 0.0f;
    p_true[r] = __expf(xt - M) / S;
    if (I >= NCLS - NTAIL) atomicAdd(&counts[I - (NCLS - NTAIL)], 1);
}

__global__ __launch_bounds__(256) void penalty_kernel(const float* __restrict__ p_true,
                                                      const int* __restrict__ labels,
                                                      const int* __restrict__ prev_counts,
                                                      const int* __restrict__ counts,
                                                      float* __restrict__ out) {
    const int i = blockIdx.x * 256 + threadIdx.x;
    const float p = p_true[i];
    const int lab = labels[i];
    float w = 1.0f;
    if (lab >= NCLS - NTAIL) {
        const int prev = prev_counts[lab];
        const int curr = counts[lab - (NCLS - NTAIL)];
        w = (prev > 0 && curr < prev) ? 4.0f
          : (prev > 0 && curr > prev) ? 2.0f
          : 3.0f;
    }
    float pen = -logf(p + 1e-7f) * (1.0f - p) * w;

    #pragma unroll
    for (int off = 32; off; off >>= 1) pen += __shfl_down(pen, off);

    __shared__ float acc[4];
    if ((threadIdx.x & 63) == 0) acc[threadIdx.x >> 6] = pen;
    __syncthreads();
    if (threadIdx.x == 0) {
        const float bs = acc[0] + acc[1] + acc[2] + acc[3];
        atomicAdd(out, bs * (0.1f / (float)BATCH));
    }
}

extern "C" void kernel_launch(void* const* d_in, const int* in_sizes, int n_in,
                              void* d_out, int out_size, void* d_ws, size_t ws_size,
                              hipStream_t stream) {
    const float* x           = (const float*)d_in[0];
    const int*   labels      = (const int*)  d_in[1];
    const int*   prev_counts = (const int*)  d_in[2];
    // d_in[3] (tail_mask) is deterministic: class >= NCLS-NTAIL — recomputed inline.

    float* out    = (float*)d_out;
    float* p_true = (float*)d_ws;
    int*   counts = (int*)((char*)d_ws + BATCH * sizeof(float));
    float* pm     = (float*)((char*)d_ws + OFF_PM);
    float* ps     = (float*)((char*)d_ws + OFF_PS);
    int*   pi     = (int*)  ((char*)d_ws + OFF_PI);

    init_kernel<<<1, 64, 0, stream>>>(out, counts);
    partial_kernel<<<BATCH, 256, 0, stream>>>(x, pm, ps, pi);
    combine_kernel<<<BATCH / 256, 256, 0, stream>>>(x, labels, pm, ps, pi, p_true, counts);
    penalty_kernel<<<BATCH / 256, 256, 0, stream>>>(p_true, labels, prev_counts, counts, out);
}